// Round 2
// baseline (1785.646 us; speedup 1.0000x reference)
//
#include <hip/hip_runtime.h>
#include <hip/hip_bf16.h>
#include <math.h>

#define NN 32768      // B*NPG nodes
#define BG 64         // graphs
#define NPGC 512      // nodes per graph
#define DD 128        // hidden dim
#define EE 524288     // edges
#define LL 10         // layers
#define EPSF 1e-5f

// ---------------- prologue: degrees, CSR build ----------------
__global__ void k_hist(const int* __restrict__ dst, int* __restrict__ cnt) {
    int e = blockIdx.x * 256 + threadIdx.x;
    atomicAdd(&cnt[dst[e]], 1);
}

__global__ void k_dinv(const int* __restrict__ cnt, float* __restrict__ dinv) {
    int n = blockIdx.x * 256 + threadIdx.x;
    dinv[n] = rsqrtf(1.0f + (float)cnt[n]);
}

// exclusive scan of cnt[NN] -> rp[NN+1], single block of 1024, 32 elems/thread
__global__ void k_scan(const int* __restrict__ cnt, int* __restrict__ rp) {
    __shared__ int s[1024];
    int t = threadIdx.x;
    int loc[32];
    int base = t * 32, tot = 0;
    for (int i = 0; i < 32; i++) { loc[i] = cnt[base + i]; tot += loc[i]; }
    s[t] = tot;
    __syncthreads();
    for (int off = 1; off < 1024; off <<= 1) {
        int add = (t >= off) ? s[t - off] : 0;
        __syncthreads();
        s[t] += add;
        __syncthreads();
    }
    int ex = (t == 0) ? 0 : s[t - 1];
    for (int i = 0; i < 32; i++) { rp[base + i] = ex; ex += loc[i]; }
    if (t == 1023) rp[NN] = ex;   // == EE
}

__global__ void k_fill(const int* __restrict__ src, const int* __restrict__ dst,
                       const float* __restrict__ dinv, const int* __restrict__ rp,
                       int* __restrict__ cursor, int* __restrict__ csr_src,
                       float* __restrict__ csr_w) {
    int e = blockIdx.x * 256 + threadIdx.x;
    int d = dst[e], sx = src[e];
    int p = atomicAdd(&cursor[d], 1);
    int i = rp[d] + p;
    csr_src[i] = sx;
    csr_w[i] = dinv[sx] * dinv[d];
}

// layer-0 "matmul": D_IN=1 outer product, hw = x * W0 row (fp32)
__global__ void k_l0(const float* __restrict__ x, const float* __restrict__ W0,
                     float* __restrict__ hw) {
    int idx = blockIdx.x * 256 + threadIdx.x;
    hw[idx] = x[idx >> 7] * W0[idx & 127];
}

// ---------------- per-layer: aggregate (gather) + BN stats ----------------
// pre[n][f] = bias[f] + dinv[n]^2*hw[n][f] + sum_e csr_w[e]*hw[csr_src[e]][f]
// also accumulates column sums / sumsq into stats (for BN).
__global__ __launch_bounds__(256) void k_agg(const float* __restrict__ hw,
        const float* __restrict__ dinv, const int* __restrict__ rp,
        const int* __restrict__ csr_src, const float* __restrict__ csr_w,
        const float* __restrict__ bias, float* __restrict__ pre,
        float* __restrict__ stats) {
    __shared__ float ssum[256], ssq[256];
    int t = threadIdx.x, f = t & 127, ns = t >> 7;   // n uniform per wave
    int nb = blockIdx.x * 16;
    float bf = bias[f];
    float lsum = 0.f, lsq = 0.f;
    for (int i = 0; i < 8; i++) {
        int n = nb + i * 2 + ns;
        float dv = dinv[n];
        float acc = fmaf(dv * dv, hw[n * 128 + f], bf);
        int e1 = rp[n + 1];
        for (int e = rp[n]; e < e1; e++)
            acc = fmaf(csr_w[e], hw[csr_src[e] * 128 + f], acc);
        pre[n * 128 + f] = acc;
        lsum += acc;
        lsq = fmaf(acc, acc, lsq);
    }
    ssum[t] = lsum; ssq[t] = lsq;
    __syncthreads();
    if (t < 128) {
        atomicAdd(&stats[t], ssum[t] + ssum[t + 128]);
        atomicAdd(&stats[128 + t], ssq[t] + ssq[t + 128]);
    }
}

// stats -> per-feature affine: h = relu(pre*sc[f] + sc[128+f])
__global__ void k_bnp(const float* __restrict__ stats, const float* __restrict__ gamma,
                      const float* __restrict__ beta, float* __restrict__ sc) {
    int f = threadIdx.x;
    float mu = stats[f] * (1.0f / NN);
    float var = stats[128 + f] * (1.0f / NN) - mu * mu;
    float s = gamma[f] * rsqrtf(var + EPSF);
    sc[f] = s;
    sc[128 + f] = fmaf(-mu, s, beta[f]);
}

// last layer: standalone BN+ReLU, fp32 in-place (pooling consumes fp32)
__global__ void k_bn_last(float* __restrict__ pre, const float* __restrict__ sc) {
    int idx = blockIdx.x * 256 + threadIdx.x;
    int f = idx & 127;
    pre[idx] = fmaxf(fmaf(pre[idx], sc[f], sc[128 + f]), 0.f);
}

// ---------------- fused BN+ReLU+matmul: hw_next = relu(bn(pre)) @ W --------
// 128x128 tile, 256 threads, 8x8 microtile, BK=64 two-chunk staging so total
// static LDS = 32KB + 32KB = 64KB (the 128KB single-stage version exceeded the
// per-workgroup LDS limit). A staged transposed [k][n] with lane-varying row
// (conflict-free LDS stores); W staged [k][f] via float4.
__global__ __launch_bounds__(256) void k_mm(const float* __restrict__ pre,
        const float* __restrict__ sc, const float* __restrict__ W,
        float* __restrict__ hw) {
    __shared__ float Hst[64 * 128];  // [kloc][n]
    __shared__ float Ws[64 * 128];   // [kloc][f]
    int t = threadIdx.x;
    int nb = blockIdx.x * 128;
    int lane = t & 63, wv = t >> 6;
    int lr = lane >> 3, lc = lane & 7;
    int n0 = (wv >> 1) * 64 + lr * 8;
    int f0 = (wv & 1) * 64 + lc * 8;
    float acc[8][8];
    #pragma unroll
    for (int i = 0; i < 8; i++)
        #pragma unroll
        for (int j = 0; j < 8; j++) acc[i][j] = 0.f;

    for (int kk = 0; kk < 128; kk += 64) {
        __syncthreads();   // fence LDS reuse from previous chunk
        for (int i = 0; i < 8; i++) {
            int idx = t + i * 256;            // 0..2047 float4 slots
            int row = idx & 127;              // node row (lane-varying store)
            int kc = (idx >> 7) * 4;          // local k base 0..60
            float4 v  = *(const float4*)(pre + (nb + row) * 128 + kk + kc);
            float4 s4 = *(const float4*)(sc + kk + kc);
            float4 h4 = *(const float4*)(sc + 128 + kk + kc);
            Hst[(kc + 0) * 128 + row] = fmaxf(fmaf(v.x, s4.x, h4.x), 0.f);
            Hst[(kc + 1) * 128 + row] = fmaxf(fmaf(v.y, s4.y, h4.y), 0.f);
            Hst[(kc + 2) * 128 + row] = fmaxf(fmaf(v.z, s4.z, h4.z), 0.f);
            Hst[(kc + 3) * 128 + row] = fmaxf(fmaf(v.w, s4.w, h4.w), 0.f);
            *(float4*)(&Ws[idx * 4]) = *(const float4*)(W + kk * 128 + idx * 4);
        }
        __syncthreads();
        for (int k = 0; k < 64; k++) {
            float4 a0 = *(const float4*)&Hst[k * 128 + n0];
            float4 a1 = *(const float4*)&Hst[k * 128 + n0 + 4];
            float4 b0 = *(const float4*)&Ws[k * 128 + f0];
            float4 b1 = *(const float4*)&Ws[k * 128 + f0 + 4];
            float a[8] = {a0.x, a0.y, a0.z, a0.w, a1.x, a1.y, a1.z, a1.w};
            float b[8] = {b0.x, b0.y, b0.z, b0.w, b1.x, b1.y, b1.z, b1.w};
            #pragma unroll
            for (int ii = 0; ii < 8; ii++)
                #pragma unroll
                for (int jj = 0; jj < 8; jj++)
                    acc[ii][jj] = fmaf(a[ii], b[jj], acc[ii][jj]);
        }
    }
    for (int ii = 0; ii < 8; ii++) {
        int n = nb + n0 + ii;
        float4 o0 = make_float4(acc[ii][0], acc[ii][1], acc[ii][2], acc[ii][3]);
        float4 o1 = make_float4(acc[ii][4], acc[ii][5], acc[ii][6], acc[ii][7]);
        *(float4*)(hw + n * 128 + f0) = o0;
        *(float4*)(hw + n * 128 + f0 + 4) = o1;
    }
}

// ---------------- pooling ----------------
// per-graph mean + tg = tanh(mean @ W_att)
__global__ void k_pool1(const float* __restrict__ h, const float* __restrict__ Watt,
                        float* __restrict__ tg) {
    __shared__ float m[128];
    int g = blockIdx.x, t = threadIdx.x;  // 128 threads
    const float* hp = h + g * NPGC * 128;
    float acc = 0.f;
    for (int n = 0; n < NPGC; n++) acc += hp[n * 128 + t];
    m[t] = acc * (1.0f / NPGC);
    __syncthreads();
    float a2 = 0.f;
    for (int k = 0; k < 128; k++) a2 = fmaf(m[k], Watt[k * 128 + t], a2);
    tg[g * 128 + t] = tanhf(a2);
}

// per-graph: coefs = sigmoid(10*<h,tg>), gf = sum coef*h, write [NPG,2D] output
__global__ void k_pool2(const float* __restrict__ h, const float* __restrict__ tg,
                        float* __restrict__ out) {
    __shared__ float tgs[128];
    __shared__ float coef[NPGC];
    __shared__ float gf[128];
    int g = blockIdx.x, t = threadIdx.x;  // 256 threads = 4 waves
    if (t < 128) tgs[t] = tg[g * 128 + t];
    __syncthreads();
    int wid = t >> 6, lane = t & 63;
    const float* hp = h + g * NPGC * 128;
    for (int n = wid; n < NPGC; n += 4) {
        float p = hp[n * 128 + lane] * tgs[lane] + hp[n * 128 + 64 + lane] * tgs[64 + lane];
        for (int off = 32; off; off >>= 1) p += __shfl_xor(p, off);
        if (lane == 0) coef[n] = 1.0f / (1.0f + expf(-10.0f * p));
    }
    __syncthreads();
    if (t < 128) {
        float acc = 0.f;
        for (int n = 0; n < NPGC; n++) acc = fmaf(coef[n], hp[n * 128 + t], acc);
        gf[t] = acc;
    }
    __syncthreads();
    float* op = out + g * NPGC * 256;
    for (int idx = t; idx < NPGC * 256; idx += 256) {
        int n = idx >> 8, c = idx & 255;
        op[idx] = (c < 128) ? hp[n * 128 + c] : gf[c - 128];
    }
}

// ---------------- host ----------------
extern "C" void kernel_launch(void* const* d_in, const int* in_sizes, int n_in,
                              void* d_out, int out_size, void* d_ws, size_t ws_size,
                              hipStream_t stream) {
    const float* x     = (const float*)d_in[0];
    const int*   esrc  = (const int*)d_in[1];
    const int*   edst  = (const int*)d_in[2];
    const float* W0    = (const float*)d_in[4];
    const float* b0    = (const float*)d_in[5];
    const float* Wr    = (const float*)d_in[6];
    const float* br    = (const float*)d_in[7];
    const float* gamma = (const float*)d_in[8];
    const float* beta  = (const float*)d_in[9];
    const float* Watt  = (const float*)d_in[10];
    float* out = (float*)d_out;
    float* ws  = (float*)d_ws;

    // workspace layout (float units)
    int*   cnt     = (int*)(ws + 0);          // NN
    int*   cursor  = (int*)(ws + 40960);      // NN
    int*   rp      = (int*)(ws + 81920);      // NN+1
    float* dinv    = ws + 122880;             // NN
    int*   csr_src = (int*)(ws + 163840);     // EE
    float* csr_w   = ws + 688128;             // EE
    float* stats   = ws + 1212416;            // LL*256
    float* sc      = ws + 1214976;            // LL*256
    float* tgbuf   = ws + 1217536;            // BG*128
    float* hw      = ws + 1228800;            // NN*DD fp32
    float* pre     = ws + 5423104;            // NN*DD fp32
    // total end: 9617408 floats = 38.5 MB

    hipMemsetAsync(cnt, 0, NN * sizeof(int), stream);
    hipMemsetAsync(cursor, 0, NN * sizeof(int), stream);
    hipMemsetAsync(stats, 0, LL * 256 * sizeof(float), stream);

    k_hist<<<EE / 256, 256, 0, stream>>>(edst, cnt);
    k_dinv<<<NN / 256, 256, 0, stream>>>(cnt, dinv);
    k_scan<<<1, 1024, 0, stream>>>(cnt, rp);
    k_fill<<<EE / 256, 256, 0, stream>>>(esrc, edst, dinv, rp, cursor, csr_src, csr_w);
    k_l0<<<(NN * DD) / 256, 256, 0, stream>>>(x, W0, hw);

    for (int l = 0; l < LL; l++) {
        const float* bias = (l == 0) ? b0 : br + (l - 1) * DD;
        k_agg<<<NN / 16, 256, 0, stream>>>(hw, dinv, rp, csr_src, csr_w, bias,
                                           pre, stats + l * 256);
        k_bnp<<<1, 128, 0, stream>>>(stats + l * 256, gamma + l * DD, beta + l * DD,
                                     sc + l * 256);
        if (l < LL - 1)
            k_mm<<<NN / 128, 256, 0, stream>>>(pre, sc + l * 256, Wr + l * DD * DD, hw);
        else
            k_bn_last<<<(NN * DD) / 256, 256, 0, stream>>>(pre, sc + l * 256);
    }
    k_pool1<<<BG, 128, 0, stream>>>(pre, Watt, tgbuf);
    k_pool2<<<BG, 256, 0, stream>>>(pre, tgbuf, out);
}

// Round 3
// 1140.620 us; speedup vs baseline: 1.5655x; 1.5655x over previous
//
#include <hip/hip_runtime.h>
#include <hip/hip_bf16.h>
#include <math.h>

#define NN 32768      // B*NPG nodes
#define BG 64         // graphs
#define NPGC 512      // nodes per graph
#define DD 128        // hidden dim
#define EE 524288     // edges
#define LL 10         // layers
#define EPSF 1e-5f

// ---------------- prologue: degrees, CSR build ----------------
__global__ void k_hist(const int* __restrict__ dst, int* __restrict__ cnt) {
    int e = blockIdx.x * 256 + threadIdx.x;
    atomicAdd(&cnt[dst[e]], 1);
}

__global__ void k_dinv(const int* __restrict__ cnt, float* __restrict__ dinv) {
    int n = blockIdx.x * 256 + threadIdx.x;
    dinv[n] = rsqrtf(1.0f + (float)cnt[n]);
}

// exclusive scan of cnt[NN] -> rp[NN+1], single block of 1024, 32 elems/thread
__global__ void k_scan(const int* __restrict__ cnt, int* __restrict__ rp) {
    __shared__ int s[1024];
    int t = threadIdx.x;
    int loc[32];
    int base = t * 32, tot = 0;
    for (int i = 0; i < 32; i++) { loc[i] = cnt[base + i]; tot += loc[i]; }
    s[t] = tot;
    __syncthreads();
    for (int off = 1; off < 1024; off <<= 1) {
        int add = (t >= off) ? s[t - off] : 0;
        __syncthreads();
        s[t] += add;
        __syncthreads();
    }
    int ex = (t == 0) ? 0 : s[t - 1];
    for (int i = 0; i < 32; i++) { rp[base + i] = ex; ex += loc[i]; }
    if (t == 1023) rp[NN] = ex;   // == EE
}

__global__ void k_fill(const int* __restrict__ src, const int* __restrict__ dst,
                       const float* __restrict__ dinv, const int* __restrict__ rp,
                       int* __restrict__ cursor, int* __restrict__ csr_src,
                       float* __restrict__ csr_w) {
    int e = blockIdx.x * 256 + threadIdx.x;
    int d = dst[e], sx = src[e];
    int p = atomicAdd(&cursor[d], 1);
    int i = rp[d] + p;
    csr_src[i] = sx;
    csr_w[i] = dinv[sx] * dinv[d];
}

// layer-0 "matmul": D_IN=1 outer product, hw = x * W0 row (fp32)
__global__ void k_l0(const float* __restrict__ x, const float* __restrict__ W0,
                     float* __restrict__ hw) {
    int idx = blockIdx.x * 256 + threadIdx.x;
    hw[idx] = x[idx >> 7] * W0[idx & 127];
}

// ---------------- per-layer: aggregate (gather) + BN stats ----------------
// One wave per node. Lane-half el=lane>>5 walks edges rp[n]+el, +2, ... ; each
// half reads the full 512B source row as 32 x float4 (coalesced). Halves are
// combined with shfl_xor(32). Two independent load chains per wave -> 8x less
// exposed L2 latency than the old scalar-per-lane serial edge loop.
__global__ __launch_bounds__(256) void k_agg(const float* __restrict__ hw,
        const float* __restrict__ dinv, const int* __restrict__ rp,
        const int* __restrict__ csr_src, const float* __restrict__ csr_w,
        const float* __restrict__ bias, float* __restrict__ pre,
        float* __restrict__ stats) {
    __shared__ float ssum[512], ssq[512];   // [wave][128]
    int t = threadIdx.x, lane = t & 63, wv = t >> 6;
    int el = lane >> 5;          // edge slot (0/1)
    int fl = (lane & 31) * 4;    // feature base for this lane
    int nb = blockIdx.x * 32;
    float4 b4 = *(const float4*)(bias + fl);
    float4 lsum = make_float4(0.f, 0.f, 0.f, 0.f);
    float4 lsq  = make_float4(0.f, 0.f, 0.f, 0.f);
    for (int i = 0; i < 8; i++) {
        int n = nb + wv * 8 + i;
        float4 acc = make_float4(0.f, 0.f, 0.f, 0.f);
        int e1 = rp[n + 1];
        for (int e = rp[n] + el; e < e1; e += 2) {
            int sx = csr_src[e];
            float w = csr_w[e];
            float4 v = *(const float4*)(hw + sx * 128 + fl);
            acc.x = fmaf(w, v.x, acc.x);
            acc.y = fmaf(w, v.y, acc.y);
            acc.z = fmaf(w, v.z, acc.z);
            acc.w = fmaf(w, v.w, acc.w);
        }
        acc.x += __shfl_xor(acc.x, 32);
        acc.y += __shfl_xor(acc.y, 32);
        acc.z += __shfl_xor(acc.z, 32);
        acc.w += __shfl_xor(acc.w, 32);
        if (el == 0) {
            float dv = dinv[n], s = dv * dv;
            float4 hv = *(const float4*)(hw + n * 128 + fl);
            acc.x = fmaf(s, hv.x, acc.x + b4.x);
            acc.y = fmaf(s, hv.y, acc.y + b4.y);
            acc.z = fmaf(s, hv.z, acc.z + b4.z);
            acc.w = fmaf(s, hv.w, acc.w + b4.w);
            *(float4*)(pre + n * 128 + fl) = acc;
            lsum.x += acc.x; lsum.y += acc.y; lsum.z += acc.z; lsum.w += acc.w;
            lsq.x = fmaf(acc.x, acc.x, lsq.x);
            lsq.y = fmaf(acc.y, acc.y, lsq.y);
            lsq.z = fmaf(acc.z, acc.z, lsq.z);
            lsq.w = fmaf(acc.w, acc.w, lsq.w);
        }
    }
    if (el == 0) {
        *(float4*)(&ssum[wv * 128 + fl]) = lsum;
        *(float4*)(&ssq[wv * 128 + fl]) = lsq;
    }
    __syncthreads();
    if (t < 128) {
        float a = ssum[t] + ssum[128 + t] + ssum[256 + t] + ssum[384 + t];
        float q = ssq[t] + ssq[128 + t] + ssq[256 + t] + ssq[384 + t];
        atomicAdd(&stats[t], a);
        atomicAdd(&stats[128 + t], q);
    }
}

// stats -> per-feature affine: h = relu(pre*sc[f] + sc[128+f])
__global__ void k_bnp(const float* __restrict__ stats, const float* __restrict__ gamma,
                      const float* __restrict__ beta, float* __restrict__ sc) {
    int f = threadIdx.x;
    float mu = stats[f] * (1.0f / NN);
    float var = stats[128 + f] * (1.0f / NN) - mu * mu;
    float s = gamma[f] * rsqrtf(var + EPSF);
    sc[f] = s;
    sc[128 + f] = fmaf(-mu, s, beta[f]);
}

// last layer: BN+ReLU in-place + per-graph column sums (for attention mean).
// 512 blocks x 256 threads; block covers 64 nodes (one-eighth of a graph).
__global__ __launch_bounds__(256) void k_bn_pool(float* __restrict__ pre,
        const float* __restrict__ sc, float* __restrict__ meansum) {
    __shared__ float ssum[256];
    int t = threadIdx.x, b = blockIdx.x;
    int f = t & 127;
    float s = sc[f], sh = sc[128 + f];
    float lsum = 0.f;
    int base = b * 8192;
    for (int i = 0; i < 32; i++) {
        int idx = base + i * 256 + t;
        float v = fmaxf(fmaf(pre[idx], s, sh), 0.f);
        pre[idx] = v;
        lsum += v;
    }
    ssum[t] = lsum;
    __syncthreads();
    if (t < 128) atomicAdd(&meansum[(b >> 3) * 128 + f], ssum[t] + ssum[t + 128]);
}

// tg = tanh((meansum/512) @ W_att), per graph
__global__ void k_tg(const float* __restrict__ meansum, const float* __restrict__ Watt,
                     float* __restrict__ tg) {
    __shared__ float m[128];
    int g = blockIdx.x, t = threadIdx.x;  // 128 threads
    m[t] = meansum[g * 128 + t] * (1.0f / NPGC);
    __syncthreads();
    float a2 = 0.f;
    for (int k = 0; k < 128; k++) a2 = fmaf(m[k], Watt[k * 128 + t], a2);
    tg[g * 128 + t] = tanhf(a2);
}

// coefs = sigmoid(10*<h,tg>) and gf += coef*h. 512 blocks, 64 nodes each.
__global__ __launch_bounds__(256) void k_coef_gf(const float* __restrict__ h,
        const float* __restrict__ tg, float* __restrict__ gf) {
    __shared__ float tgs[128];
    __shared__ float coef[64];
    int t = threadIdx.x, b = blockIdx.x;
    int g = b >> 3, n0 = (b & 7) * 64;        // local node base within graph
    if (t < 128) tgs[t] = tg[g * 128 + t];
    __syncthreads();
    int wid = t >> 6, lane = t & 63;
    const float* hp = h + (size_t)g * NPGC * 128;
    for (int j = wid; j < 64; j += 4) {
        int n = n0 + j;
        float p = hp[n * 128 + lane] * tgs[lane] + hp[n * 128 + 64 + lane] * tgs[64 + lane];
        for (int off = 32; off; off >>= 1) p += __shfl_xor(p, off);
        if (lane == 0) coef[j] = 1.0f / (1.0f + expf(-10.0f * p));
    }
    __syncthreads();
    int f = t & 127, half = t >> 7;           // half: nodes 0..31 / 32..63
    float acc = 0.f;
    for (int j = 0; j < 32; j++) {
        int jj = half * 32 + j;
        acc = fmaf(coef[jj], hp[(n0 + jj) * 128 + f], acc);
    }
    atomicAdd(&gf[g * 128 + f], acc);
}

// output writer: out[g][n][0:128]=h, out[g][n][128:256]=gf[g]; float4 flat
__global__ void k_out(const float* __restrict__ h, const float* __restrict__ gf,
                      float* __restrict__ out) {
    int idx = blockIdx.x * 256 + threadIdx.x;  // float4 slot, 64 per node
    int c4 = (idx & 63) * 4;
    int n = idx >> 6;                          // global node
    int g = n >> 9;
    float4 v = (c4 < 128) ? *(const float4*)(h + (size_t)n * 128 + c4)
                          : *(const float4*)(gf + g * 128 + (c4 - 128));
    *(float4*)(out + (size_t)idx * 4) = v;
}

// ---------------- fused BN+ReLU+matmul: hw_next = relu(bn(pre)) @ W --------
// 128x128 tile, 256 threads, 8x8 microtile, BK=64 two-chunk staging, 64KB LDS.
__global__ __launch_bounds__(256) void k_mm(const float* __restrict__ pre,
        const float* __restrict__ sc, const float* __restrict__ W,
        float* __restrict__ hw) {
    __shared__ float Hst[64 * 128];  // [kloc][n]
    __shared__ float Ws[64 * 128];   // [kloc][f]
    int t = threadIdx.x;
    int nb = blockIdx.x * 128;
    int lane = t & 63, wv = t >> 6;
    int lr = lane >> 3, lc = lane & 7;
    int n0 = (wv >> 1) * 64 + lr * 8;
    int f0 = (wv & 1) * 64 + lc * 8;
    float acc[8][8];
    #pragma unroll
    for (int i = 0; i < 8; i++)
        #pragma unroll
        for (int j = 0; j < 8; j++) acc[i][j] = 0.f;

    for (int kk = 0; kk < 128; kk += 64) {
        __syncthreads();
        for (int i = 0; i < 8; i++) {
            int idx = t + i * 256;
            int row = idx & 127;
            int kc = (idx >> 7) * 4;
            float4 v  = *(const float4*)(pre + (nb + row) * 128 + kk + kc);
            float4 s4 = *(const float4*)(sc + kk + kc);
            float4 h4 = *(const float4*)(sc + 128 + kk + kc);
            Hst[(kc + 0) * 128 + row] = fmaxf(fmaf(v.x, s4.x, h4.x), 0.f);
            Hst[(kc + 1) * 128 + row] = fmaxf(fmaf(v.y, s4.y, h4.y), 0.f);
            Hst[(kc + 2) * 128 + row] = fmaxf(fmaf(v.z, s4.z, h4.z), 0.f);
            Hst[(kc + 3) * 128 + row] = fmaxf(fmaf(v.w, s4.w, h4.w), 0.f);
            *(float4*)(&Ws[idx * 4]) = *(const float4*)(W + kk * 128 + idx * 4);
        }
        __syncthreads();
        for (int k = 0; k < 64; k++) {
            float4 a0 = *(const float4*)&Hst[k * 128 + n0];
            float4 a1 = *(const float4*)&Hst[k * 128 + n0 + 4];
            float4 b0 = *(const float4*)&Ws[k * 128 + f0];
            float4 b1 = *(const float4*)&Ws[k * 128 + f0 + 4];
            float a[8] = {a0.x, a0.y, a0.z, a0.w, a1.x, a1.y, a1.z, a1.w};
            float b[8] = {b0.x, b0.y, b0.z, b0.w, b1.x, b1.y, b1.z, b1.w};
            #pragma unroll
            for (int ii = 0; ii < 8; ii++)
                #pragma unroll
                for (int jj = 0; jj < 8; jj++)
                    acc[ii][jj] = fmaf(a[ii], b[jj], acc[ii][jj]);
        }
    }
    for (int ii = 0; ii < 8; ii++) {
        int n = nb + n0 + ii;
        float4 o0 = make_float4(acc[ii][0], acc[ii][1], acc[ii][2], acc[ii][3]);
        float4 o1 = make_float4(acc[ii][4], acc[ii][5], acc[ii][6], acc[ii][7]);
        *(float4*)(hw + n * 128 + f0) = o0;
        *(float4*)(hw + n * 128 + f0 + 4) = o1;
    }
}

// ---------------- host ----------------
extern "C" void kernel_launch(void* const* d_in, const int* in_sizes, int n_in,
                              void* d_out, int out_size, void* d_ws, size_t ws_size,
                              hipStream_t stream) {
    const float* x     = (const float*)d_in[0];
    const int*   esrc  = (const int*)d_in[1];
    const int*   edst  = (const int*)d_in[2];
    const float* W0    = (const float*)d_in[4];
    const float* b0    = (const float*)d_in[5];
    const float* Wr    = (const float*)d_in[6];
    const float* br    = (const float*)d_in[7];
    const float* gamma = (const float*)d_in[8];
    const float* beta  = (const float*)d_in[9];
    const float* Watt  = (const float*)d_in[10];
    float* out = (float*)d_out;
    float* ws  = (float*)d_ws;

    // workspace layout (float units)
    int*   cnt     = (int*)(ws + 0);          // NN
    int*   cursor  = (int*)(ws + 40960);      // NN
    int*   rp      = (int*)(ws + 81920);      // NN+1
    float* dinv    = ws + 122880;             // NN
    int*   csr_src = (int*)(ws + 163840);     // EE
    float* csr_w   = ws + 688128;             // EE
    float* stats   = ws + 1212416;            // LL*256
    float* sc      = ws + 1214976;            // LL*256
    float* tgbuf   = ws + 1217536;            // BG*128
    float* meansum = ws + 1225728;            // BG*128
    float* gf      = ws + 1233920;            // BG*128
    float* hw      = ws + 1245184;            // NN*DD fp32
    float* pre     = ws + 5439488;            // NN*DD fp32
    // end: 9633792 floats = 38.5 MB

    hipMemsetAsync(cnt, 0, NN * sizeof(int), stream);
    hipMemsetAsync(cursor, 0, NN * sizeof(int), stream);
    hipMemsetAsync(stats, 0, LL * 256 * sizeof(float), stream);
    hipMemsetAsync(meansum, 0, BG * 128 * sizeof(float), stream);
    hipMemsetAsync(gf, 0, BG * 128 * sizeof(float), stream);

    k_hist<<<EE / 256, 256, 0, stream>>>(edst, cnt);
    k_dinv<<<NN / 256, 256, 0, stream>>>(cnt, dinv);
    k_scan<<<1, 1024, 0, stream>>>(cnt, rp);
    k_fill<<<EE / 256, 256, 0, stream>>>(esrc, edst, dinv, rp, cursor, csr_src, csr_w);
    k_l0<<<(NN * DD) / 256, 256, 0, stream>>>(x, W0, hw);

    for (int l = 0; l < LL; l++) {
        const float* bias = (l == 0) ? b0 : br + (l - 1) * DD;
        k_agg<<<NN / 32, 256, 0, stream>>>(hw, dinv, rp, csr_src, csr_w, bias,
                                           pre, stats + l * 256);
        k_bnp<<<1, 128, 0, stream>>>(stats + l * 256, gamma + l * DD, beta + l * DD,
                                     sc + l * 256);
        if (l < LL - 1)
            k_mm<<<NN / 128, 256, 0, stream>>>(pre, sc + l * 256, Wr + l * DD * DD, hw);
        else
            k_bn_pool<<<512, 256, 0, stream>>>(pre, sc + l * 256, meansum);
    }
    k_tg<<<BG, 128, 0, stream>>>(meansum, Watt, tgbuf);
    k_coef_gf<<<512, 256, 0, stream>>>(pre, tgbuf, gf);
    k_out<<<NN * 64 / 256, 256, 0, stream>>>(pre, gf, out);
}

// Round 4
// 857.813 us; speedup vs baseline: 2.0816x; 1.3297x over previous
//
#include <hip/hip_runtime.h>
#include <hip/hip_bf16.h>
#include <math.h>

#define NN 32768      // B*NPG nodes
#define BG 64         // graphs
#define NPGC 512      // nodes per graph
#define DD 128        // hidden dim
#define EE 524288     // edges
#define LL 10         // layers
#define EPSF 1e-5f

// XCD-aware block->work swizzle: presumed round-robin blockIdx%8 -> XCD.
// All work for graph g is mapped to blocks with blockIdx%8 == g%8 so the
// graph's 256KB hw slice stays resident in ONE XCD's L2 across the whole
// layer pipeline (k_agg gather + k_mm read/write). Perf heuristic only.

// ---------------- prologue: degrees, CSR build ----------------
__global__ void k_hist(const int* __restrict__ dst, int* __restrict__ cnt) {
    int e = blockIdx.x * 256 + threadIdx.x;
    atomicAdd(&cnt[dst[e]], 1);
}

__global__ void k_dinv(const int* __restrict__ cnt, float* __restrict__ dinv) {
    int n = blockIdx.x * 256 + threadIdx.x;
    dinv[n] = rsqrtf(1.0f + (float)cnt[n]);
}

// exclusive scan of cnt[NN] -> rp[NN+1], single block of 1024, 32 elems/thread
__global__ void k_scan(const int* __restrict__ cnt, int* __restrict__ rp) {
    __shared__ int s[1024];
    int t = threadIdx.x;
    int loc[32];
    int base = t * 32, tot = 0;
    for (int i = 0; i < 32; i++) { loc[i] = cnt[base + i]; tot += loc[i]; }
    s[t] = tot;
    __syncthreads();
    for (int off = 1; off < 1024; off <<= 1) {
        int add = (t >= off) ? s[t - off] : 0;
        __syncthreads();
        s[t] += add;
        __syncthreads();
    }
    int ex = (t == 0) ? 0 : s[t - 1];
    for (int i = 0; i < 32; i++) { rp[base + i] = ex; ex += loc[i]; }
    if (t == 1023) rp[NN] = ex;   // == EE
}

__global__ void k_fill(const int* __restrict__ src, const int* __restrict__ dst,
                       const float* __restrict__ dinv, const int* __restrict__ rp,
                       int* __restrict__ cursor, int* __restrict__ csr_src,
                       float* __restrict__ csr_w) {
    int e = blockIdx.x * 256 + threadIdx.x;
    int d = dst[e], sx = src[e];
    int p = atomicAdd(&cursor[d], 1);
    int i = rp[d] + p;
    csr_src[i] = sx;
    csr_w[i] = dinv[sx] * dinv[d];
}

// layer-0 "matmul": D_IN=1 outer product, hw = x * W0 row (fp32)
__global__ void k_l0(const float* __restrict__ x, const float* __restrict__ W0,
                     float* __restrict__ hw) {
    int idx = blockIdx.x * 256 + threadIdx.x;
    hw[idx] = x[idx >> 7] * W0[idx & 127];
}

// ---------------- per-layer: aggregate (gather) + BN stats ----------------
// One wave per node; lane-half el walks alternate edges; each half reads the
// 512B source row as 32 x float4 (coalesced); halves combined via shfl_xor(32).
// 1024 blocks, XCD-swizzled: block handles 32 nodes of graph g == blockIdx%8 (mod 8).
__global__ __launch_bounds__(256) void k_agg(const float* __restrict__ hw,
        const float* __restrict__ dinv, const int* __restrict__ rp,
        const int* __restrict__ csr_src, const float* __restrict__ csr_w,
        const float* __restrict__ bias, float* __restrict__ pre,
        float* __restrict__ stats) {
    __shared__ float ssum[512], ssq[512];   // [wave][128]
    int t = threadIdx.x, lane = t & 63, wv = t >> 6;
    int el = lane >> 5;          // edge slot (0/1)
    int fl = (lane & 31) * 4;    // feature base for this lane
    int b = blockIdx.x, r = b & 7, q = b >> 3;      // q: 0..127
    int g = r + 8 * (q & 7);                        // graph 0..63
    int nb = g * NPGC + (q >> 3) * 32;              // 16 chunks of 32 nodes
    float4 b4 = *(const float4*)(bias + fl);
    float4 lsum = make_float4(0.f, 0.f, 0.f, 0.f);
    float4 lsq  = make_float4(0.f, 0.f, 0.f, 0.f);
    for (int i = 0; i < 8; i++) {
        int n = nb + wv * 8 + i;
        float4 acc = make_float4(0.f, 0.f, 0.f, 0.f);
        int e1 = rp[n + 1];
        for (int e = rp[n] + el; e < e1; e += 2) {
            int sx = csr_src[e];
            float w = csr_w[e];
            float4 v = *(const float4*)(hw + sx * 128 + fl);
            acc.x = fmaf(w, v.x, acc.x);
            acc.y = fmaf(w, v.y, acc.y);
            acc.z = fmaf(w, v.z, acc.z);
            acc.w = fmaf(w, v.w, acc.w);
        }
        acc.x += __shfl_xor(acc.x, 32);
        acc.y += __shfl_xor(acc.y, 32);
        acc.z += __shfl_xor(acc.z, 32);
        acc.w += __shfl_xor(acc.w, 32);
        if (el == 0) {
            float dv = dinv[n], s = dv * dv;
            float4 hv = *(const float4*)(hw + n * 128 + fl);
            acc.x = fmaf(s, hv.x, acc.x + b4.x);
            acc.y = fmaf(s, hv.y, acc.y + b4.y);
            acc.z = fmaf(s, hv.z, acc.z + b4.z);
            acc.w = fmaf(s, hv.w, acc.w + b4.w);
            *(float4*)(pre + n * 128 + fl) = acc;
            lsum.x += acc.x; lsum.y += acc.y; lsum.z += acc.z; lsum.w += acc.w;
            lsq.x = fmaf(acc.x, acc.x, lsq.x);
            lsq.y = fmaf(acc.y, acc.y, lsq.y);
            lsq.z = fmaf(acc.z, acc.z, lsq.z);
            lsq.w = fmaf(acc.w, acc.w, lsq.w);
        }
    }
    if (el == 0) {
        *(float4*)(&ssum[wv * 128 + fl]) = lsum;
        *(float4*)(&ssq[wv * 128 + fl]) = lsq;
    }
    __syncthreads();
    if (t < 128) {
        float a = ssum[t] + ssum[128 + t] + ssum[256 + t] + ssum[384 + t];
        float qq = ssq[t] + ssq[128 + t] + ssq[256 + t] + ssq[384 + t];
        atomicAdd(&stats[t], a);
        atomicAdd(&stats[128 + t], qq);
    }
}

// ---------------- fused BN+ReLU+matmul: hw_next = relu(bn(pre)) @ W --------
// 64x128 tile, 512 blocks (2/CU), 256 threads, 4x8 microtile, BK=64, 48KB LDS.
// BN affine computed inline from stats (k_bnp folded in). XCD-swizzled.
__global__ __launch_bounds__(256) void k_mm(const float* __restrict__ pre,
        const float* __restrict__ stats, const float* __restrict__ gamma,
        const float* __restrict__ beta, const float* __restrict__ W,
        float* __restrict__ hw) {
    __shared__ float Hst[64 * 64];   // [kloc][n]  16KB
    __shared__ float Ws[64 * 128];   // [kloc][f]  32KB
    __shared__ float scL[256];
    int t = threadIdx.x;
    int b = blockIdx.x, r = b & 7, q = b >> 3;      // q: 0..63
    int g = r + 8 * (q & 7);
    int nb = g * NPGC + (q >> 3) * 64;              // 8 chunks of 64 nodes
    if (t < 128) {
        float mu = stats[t] * (1.0f / NN);
        float var = stats[128 + t] * (1.0f / NN) - mu * mu;
        float s = gamma[t] * rsqrtf(var + EPSF);
        scL[t] = s;
        scL[128 + t] = fmaf(-mu, s, beta[t]);
    }
    int rq = t >> 4, cq = t & 15;
    int r0 = rq * 4, c0 = cq * 8;
    float acc[4][8];
    #pragma unroll
    for (int i = 0; i < 4; i++)
        #pragma unroll
        for (int j = 0; j < 8; j++) acc[i][j] = 0.f;

    for (int kk = 0; kk < 128; kk += 64) {
        __syncthreads();   // also publishes scL on first iteration
        for (int i = 0; i < 4; i++) {
            int idx = t + i * 256;            // 1024 float4 slots
            int row = idx & 63;
            int kc = (idx >> 6) * 4;          // 0..60
            float4 v  = *(const float4*)(pre + (nb + row) * 128 + kk + kc);
            float4 s4 = *(const float4*)(&scL[kk + kc]);
            float4 h4 = *(const float4*)(&scL[128 + kk + kc]);
            Hst[(kc + 0) * 64 + row] = fmaxf(fmaf(v.x, s4.x, h4.x), 0.f);
            Hst[(kc + 1) * 64 + row] = fmaxf(fmaf(v.y, s4.y, h4.y), 0.f);
            Hst[(kc + 2) * 64 + row] = fmaxf(fmaf(v.z, s4.z, h4.z), 0.f);
            Hst[(kc + 3) * 64 + row] = fmaxf(fmaf(v.w, s4.w, h4.w), 0.f);
        }
        for (int i = 0; i < 8; i++) {
            int idx = t + i * 256;            // 2048 float4 slots
            *(float4*)(&Ws[idx * 4]) = *(const float4*)(W + kk * 128 + idx * 4);
        }
        __syncthreads();
        for (int k = 0; k < 64; k++) {
            float4 a4 = *(const float4*)&Hst[k * 64 + r0];
            float4 b0 = *(const float4*)&Ws[k * 128 + c0];
            float4 b1 = *(const float4*)&Ws[k * 128 + c0 + 4];
            float a[4] = {a4.x, a4.y, a4.z, a4.w};
            float bb[8] = {b0.x, b0.y, b0.z, b0.w, b1.x, b1.y, b1.z, b1.w};
            #pragma unroll
            for (int ii = 0; ii < 4; ii++)
                #pragma unroll
                for (int jj = 0; jj < 8; jj++)
                    acc[ii][jj] = fmaf(a[ii], bb[jj], acc[ii][jj]);
        }
    }
    for (int ii = 0; ii < 4; ii++) {
        int n = nb + r0 + ii;
        float4 o0 = make_float4(acc[ii][0], acc[ii][1], acc[ii][2], acc[ii][3]);
        float4 o1 = make_float4(acc[ii][4], acc[ii][5], acc[ii][6], acc[ii][7]);
        *(float4*)(hw + n * 128 + c0) = o0;
        *(float4*)(hw + n * 128 + c0 + 4) = o1;
    }
}

// last layer: BN+ReLU in-place + per-graph column sums. 512 blocks, swizzled.
__global__ __launch_bounds__(256) void k_bn_pool(float* __restrict__ pre,
        const float* __restrict__ stats, const float* __restrict__ gamma,
        const float* __restrict__ beta, float* __restrict__ meansum) {
    __shared__ float ssum[256];
    __shared__ float scL[256];
    int t = threadIdx.x;
    int b = blockIdx.x, r = b & 7, q = b >> 3;
    int g = r + 8 * (q & 7);
    int nb = g * NPGC + (q >> 3) * 64;
    if (t < 128) {
        float mu = stats[t] * (1.0f / NN);
        float var = stats[128 + t] * (1.0f / NN) - mu * mu;
        float s = gamma[t] * rsqrtf(var + EPSF);
        scL[t] = s;
        scL[128 + t] = fmaf(-mu, s, beta[t]);
    }
    __syncthreads();
    int f = t & 127;
    float s = scL[f], sh = scL[128 + f];
    float lsum = 0.f;
    int base = nb * 128;
    for (int i = 0; i < 32; i++) {
        int idx = base + i * 256 + t;
        float v = fmaxf(fmaf(pre[idx], s, sh), 0.f);
        pre[idx] = v;
        lsum += v;
    }
    ssum[t] = lsum;
    __syncthreads();
    if (t < 128) atomicAdd(&meansum[g * 128 + f], ssum[t] + ssum[t + 128]);
}

// tg = tanh((meansum/512) @ W_att), per graph
__global__ void k_tg(const float* __restrict__ meansum, const float* __restrict__ Watt,
                     float* __restrict__ tg) {
    __shared__ float m[128];
    int g = blockIdx.x, t = threadIdx.x;  // 128 threads
    m[t] = meansum[g * 128 + t] * (1.0f / NPGC);
    __syncthreads();
    float a2 = 0.f;
    for (int k = 0; k < 128; k++) a2 = fmaf(m[k], Watt[k * 128 + t], a2);
    tg[g * 128 + t] = tanhf(a2);
}

// coefs = sigmoid(10*<h,tg>) and gf += coef*h. 512 blocks, 64 nodes each, swizzled.
__global__ __launch_bounds__(256) void k_coef_gf(const float* __restrict__ h,
        const float* __restrict__ tg, float* __restrict__ gf) {
    __shared__ float tgs[128];
    __shared__ float coef[64];
    int t = threadIdx.x;
    int b = blockIdx.x, r = b & 7, q = b >> 3;
    int g = r + 8 * (q & 7);
    int n0 = (q >> 3) * 64;                   // local node base within graph
    if (t < 128) tgs[t] = tg[g * 128 + t];
    __syncthreads();
    int wid = t >> 6, lane = t & 63;
    const float* hp = h + (size_t)g * NPGC * 128;
    for (int j = wid; j < 64; j += 4) {
        int n = n0 + j;
        float p = hp[n * 128 + lane] * tgs[lane] + hp[n * 128 + 64 + lane] * tgs[64 + lane];
        for (int off = 32; off; off >>= 1) p += __shfl_xor(p, off);
        if (lane == 0) coef[j] = 1.0f / (1.0f + expf(-10.0f * p));
    }
    __syncthreads();
    int f = t & 127, half = t >> 7;           // half: nodes 0..31 / 32..63
    float acc = 0.f;
    for (int j = 0; j < 32; j++) {
        int jj = half * 32 + j;
        acc = fmaf(coef[jj], hp[(n0 + jj) * 128 + f], acc);
    }
    atomicAdd(&gf[g * 128 + f], acc);
}

// output writer: out[g][n][0:128]=h, out[g][n][128:256]=gf[g]; float4 flat
__global__ void k_out(const float* __restrict__ h, const float* __restrict__ gf,
                      float* __restrict__ out) {
    int idx = blockIdx.x * 256 + threadIdx.x;  // float4 slot, 64 per node
    int c4 = (idx & 63) * 4;
    int n = idx >> 6;                          // global node
    int g = n >> 9;
    float4 v = (c4 < 128) ? *(const float4*)(h + (size_t)n * 128 + c4)
                          : *(const float4*)(gf + g * 128 + (c4 - 128));
    *(float4*)(out + (size_t)idx * 4) = v;
}

// ---------------- host ----------------
extern "C" void kernel_launch(void* const* d_in, const int* in_sizes, int n_in,
                              void* d_out, int out_size, void* d_ws, size_t ws_size,
                              hipStream_t stream) {
    const float* x     = (const float*)d_in[0];
    const int*   esrc  = (const int*)d_in[1];
    const int*   edst  = (const int*)d_in[2];
    const float* W0    = (const float*)d_in[4];
    const float* b0    = (const float*)d_in[5];
    const float* Wr    = (const float*)d_in[6];
    const float* br    = (const float*)d_in[7];
    const float* gamma = (const float*)d_in[8];
    const float* beta  = (const float*)d_in[9];
    const float* Watt  = (const float*)d_in[10];
    float* out = (float*)d_out;
    float* ws  = (float*)d_ws;

    // workspace layout (float units)
    int*   cnt     = (int*)(ws + 0);          // NN
    int*   cursor  = (int*)(ws + 40960);      // NN
    int*   rp      = (int*)(ws + 81920);      // NN+1
    float* dinv    = ws + 122880;             // NN
    int*   csr_src = (int*)(ws + 163840);     // EE
    float* csr_w   = ws + 688128;             // EE
    float* stats   = ws + 1212416;            // LL*256
    float* tgbuf   = ws + 1217536;            // BG*128
    float* meansum = ws + 1225728;            // BG*128
    float* gf      = ws + 1233920;            // BG*128
    float* hw      = ws + 1245184;            // NN*DD fp32
    float* pre     = ws + 5439488;            // NN*DD fp32
    // end: 9633792 floats = 38.5 MB

    hipMemsetAsync(cnt, 0, NN * sizeof(int), stream);
    hipMemsetAsync(cursor, 0, NN * sizeof(int), stream);
    hipMemsetAsync(stats, 0, LL * 256 * sizeof(float), stream);
    hipMemsetAsync(meansum, 0, BG * 128 * sizeof(float), stream);
    hipMemsetAsync(gf, 0, BG * 128 * sizeof(float), stream);

    k_hist<<<EE / 256, 256, 0, stream>>>(edst, cnt);
    k_dinv<<<NN / 256, 256, 0, stream>>>(cnt, dinv);
    k_scan<<<1, 1024, 0, stream>>>(cnt, rp);
    k_fill<<<EE / 256, 256, 0, stream>>>(esrc, edst, dinv, rp, cursor, csr_src, csr_w);
    k_l0<<<(NN * DD) / 256, 256, 0, stream>>>(x, W0, hw);

    for (int l = 0; l < LL; l++) {
        const float* bias = (l == 0) ? b0 : br + (l - 1) * DD;
        k_agg<<<NN / 32, 256, 0, stream>>>(hw, dinv, rp, csr_src, csr_w, bias,
                                           pre, stats + l * 256);
        if (l < LL - 1)
            k_mm<<<NN / 64, 256, 0, stream>>>(pre, stats + l * 256, gamma + l * DD,
                                              beta + l * DD, Wr + l * DD * DD, hw);
        else
            k_bn_pool<<<NN / 64, 256, 0, stream>>>(pre, stats + l * 256, gamma + l * DD,
                                                   beta + l * DD, meansum);
    }
    k_tg<<<BG, 128, 0, stream>>>(meansum, Watt, tgbuf);
    k_coef_gf<<<NN / 64, 256, 0, stream>>>(pre, tgbuf, gf);
    k_out<<<NN * 64 / 256, 256, 0, stream>>>(pre, gf, out);
}